// Round 11
// baseline (81.751 us; speedup 1.0000x reference)
//
#include <hip/hip_runtime.h>
#include <math.h>

// Problem constants: b=2, h=4, n_tot=585, d=128, n=512, k=8
// Levels: L0 rows [0,512), L1 [512,576), L2 [576,584), L3 {584}
// Lane layout: s = lane>>3 (key slot 0..7), c = lane&7 (dim chunk of 16)
//
// Masked-entry algebra (exact, R8-proven): every masked selector slot
// contributes logit q.K[0] and value row 0; cnt identical entries == one
// term with weight cnt*e0.  Updated row 0 == (2/3)*V[0].
#define D 128
#define NTOT 585
#define SCALE 0.08838834764831845f  // 1/sqrt(128)
#define THIRD 0.33333333333333333f
#define LROW 132                    // LDS row stride (pad 4): conflict-free b128

__device__ __forceinline__ float rsum_c(float v) {  // sum over c (strides 1,2,4)
    v += __shfl_xor(v, 1, 64);
    v += __shfl_xor(v, 2, 64);
    v += __shfl_xor(v, 4, 64);
    return v;
}
__device__ __forceinline__ float rsum_s(float v) {  // sum over s (strides 8,16,32)
    v += __shfl_xor(v, 8, 64);
    v += __shfl_xor(v, 16, 64);
    v += __shfl_xor(v, 32, 64);
    return v;
}
__device__ __forceinline__ float rmax_s(float v) {
    v = fmaxf(v, __shfl_xor(v, 8, 64));
    v = fmaxf(v, __shfl_xor(v, 16, 64));
    v = fmaxf(v, __shfl_xor(v, 32, 64));
    return v;
}
__device__ __forceinline__ float dot16(const float4 q[4], const float* __restrict__ row, int c) {
    const float4* k = (const float4*)(row + (c << 4));
    float4 k0 = k[0], k1 = k[1], k2 = k[2], k3 = k[3];
    float p0 = q[0].x * k0.x + q[0].y * k0.y + q[0].z * k0.z + q[0].w * k0.w;
    float p1 = q[1].x * k1.x + q[1].y * k1.y + q[1].z * k1.z + q[1].w * k1.w;
    float p2 = q[2].x * k2.x + q[2].y * k2.y + q[2].z * k2.z + q[2].w * k2.w;
    float p3 = q[3].x * k3.x + q[3].y * k3.y + q[3].z * k3.z + q[3].w * k3.w;
    return (p0 + p1) + (p2 + p3);
}
__device__ __forceinline__ void vacc(float w, const float* __restrict__ row, int c, float4 acc[4]) {
    const float4* v = (const float4*)(row + (c << 4));
#pragma unroll
    for (int u = 0; u < 4; ++u) {
        float4 t = v[u];
        acc[u].x += w * t.x; acc[u].y += w * t.y; acc[u].z += w * t.z; acc[u].w += w * t.w;
    }
}
__device__ __forceinline__ void vacc_reg(float w, const float4 vv[4], float4 acc[4]) {
#pragma unroll
    for (int u = 0; u < 4; ++u) {
        acc[u].x += w * vv[u].x; acc[u].y += w * vv[u].y;
        acc[u].z += w * vv[u].z; acc[u].w += w * vv[u].w;
    }
}
__device__ __forceinline__ void loadq(const float* __restrict__ qrow, int c, float4 q[4]) {
    const float4* qp = (const float4*)(qrow + (c << 4));
#pragma unroll
    for (int u = 0; u < 4; ++u) q[u] = qp[u];
}
__device__ __forceinline__ void butterfly_acc(float4 acc[4]) {
#pragma unroll
    for (int u = 0; u < 4; ++u) {
        acc[u].x = rsum_s(acc[u].x);
        acc[u].y = rsum_s(acc[u].y);
        acc[u].z = rsum_s(acc[u].z);
        acc[u].w = rsum_s(acc[u].w);
    }
}

// =============== Kernel A: level 0, one sib-group per block ==================
// 512 blocks (8 bh x 64 groups) x 512 threads = 8 waves, query i = 8*gb + w.
// Block-uniform anc bound g == gb -> stage only 9+g rows (avg 41, max 73):
// LDS slots [0,8) = sib rows 8g..8g+7, slot 8+j = anc row 512+j (j<g),
// slot 72 = row 0.  77 KB -> 2 blocks/CU (balance slack + overlap).
__global__ __launch_bounds__(512) void level0_lds(const float* __restrict__ Q,
                                                  const float* __restrict__ K,
                                                  const float* __restrict__ V,
                                                  float* __restrict__ Out) {
    __shared__ float Ks[73 * LROW];
    __shared__ float Vs[73 * LROW];
    const int tid = threadIdx.x;
    const int lane = tid & 63;
    const int s = lane >> 3, c = lane & 7;
    const int bh = blockIdx.x >> 6;
    const int g = blockIdx.x & 63;          // sib group == anc bound
    const float* Qb = Q + (size_t)bh * NTOT * D;
    const float* Kb = K + (size_t)bh * NTOT * D;
    const float* Vb = V + (size_t)bh * NTOT * D;
    float* Ob = Out + (size_t)bh * NTOT * D;

    // ---- stage 9+g K rows + 9+g V rows (coalesced float4) ----
    const int nrows = 9 + g;
    for (int t = tid; t < nrows * 32; t += 512) {
        const int r = t >> 5, col = (t & 31) << 2;
        int src, slot;
        if (r < 8)            { src = 8 * g + r;     slot = r; }
        else if (r < 8 + g)   { src = 512 + (r - 8); slot = r; }
        else                  { src = 0;             slot = 72; }
        *(float4*)(&Ks[slot * LROW + col]) = *(const float4*)(Kb + (size_t)src * D + col);
        *(float4*)(&Vs[slot * LROW + col]) = *(const float4*)(Vb + (size_t)src * D + col);
    }
    __syncthreads();

    const int w = tid >> 6;       // wave 0..7
    const int i = 8 * g + w;      // this wave's query
    const int sl = w;             // sib pass slots: s <= sl

    float4 q4[4];
    loadq(Qb + (size_t)i * D, c, q4);
    float4 acc[4] = {{0,0,0,0},{0,0,0,0},{0,0,0,0},{0,0,0,0}};
    const float lg0 = rsum_c(dot16(q4, &Ks[72 * LROW], c)) * SCALE;

    // ------------------------------ sib -------------------------------------
    {
        float lg = -1e30f;
        if (s <= sl)
            lg = rsum_c(dot16(q4, &Ks[s * LROW], c)) * SCALE;
        const float m = fmaxf(rmax_s(lg), lg0);
        const float e = (s <= sl) ? __expf(lg - m) : 0.f;
        const float e0 = __expf(lg0 - m);
        float zp = e;
        if (s == 0) zp += (float)(7 - sl) * e0;
        const float inv = 1.f / rsum_s(zp);
        if (s <= sl) vacc(e * inv, &Vs[s * LROW], c, acc);
        if (s == 0 && sl < 7) vacc((float)(7 - sl) * e0 * inv, &Vs[72 * LROW], c, acc);
    }

    // ------------------------------ anc -------------------------------------
    // softmax over {q.K[512+j] : j<g} ∪ (64-g) copies of lg0 (value V[0]).
    {
        float lgA[8];
        float mloc = lg0;
#pragma unroll
        for (int R = 0; R < 4; ++R) {
            if (16 * R < g) {                       // block-uniform guard
#pragma unroll
                for (int rr = 0; rr < 2; ++rr) {
                    const int r = 2 * R + rr;
                    const int j = 8 * r + s;
                    float lg = -1e30f;
                    if (j < g)                       // octet-uniform
                        lg = rsum_c(dot16(q4, &Ks[(8 + j) * LROW], c)) * SCALE;
                    lgA[r] = lg;
                    mloc = fmaxf(mloc, lg);
                }
            } else { lgA[2 * R] = -1e30f; lgA[2 * R + 1] = -1e30f; }
        }
        const float m = rmax_s(mloc);
        const float e0 = __expf(lg0 - m);
        float zp = (s == 0) ? (float)(64 - g) * e0 : 0.f;
        float eA[8];
#pragma unroll
        for (int R = 0; R < 4; ++R) {
            if (16 * R < g) {
#pragma unroll
                for (int rr = 0; rr < 2; ++rr) {
                    const int r = 2 * R + rr;
                    eA[r] = (lgA[r] > -1e29f) ? __expf(lgA[r] - m) : 0.f;
                    zp += eA[r];
                }
            }
        }
        const float inv = 1.f / rsum_s(zp);
#pragma unroll
        for (int R = 0; R < 4; ++R) {
            if (16 * R < g) {
#pragma unroll
                for (int rr = 0; rr < 2; ++rr) {
                    const int r = 2 * R + rr;
                    const int j = 8 * r + s;
                    if (j < g) vacc(eA[r] * inv, &Vs[(8 + j) * LROW], c, acc);
                }
            }
        }
        if (s == 0) vacc((float)(64 - g) * e0 * inv, &Vs[72 * LROW], c, acc);
    }
    butterfly_acc(acc);
    if (s == 0) {
        float4* orow = (float4*)(Ob + (size_t)i * D + (c << 4));
#pragma unroll
        for (int u = 0; u < 4; ++u)
            orow[u] = make_float4(acc[u].x * THIRD, acc[u].y * THIRD,
                                  acc[u].z * THIRD, acc[u].w * THIRD);
    }
}

// ============ Kernel B: levels 1+2+3 with full LDS staging (R10) =============
// 32 blocks (4 per bh) x 1024 threads = 16 waves, 1 L1 query/wave.
// LDS rows: [0,64) = global 512..575, [64,72) = 576..583, 72 = row 0. 77 KB.
// v0n analytic = (2/3)*V[0]; o0 = Out row 8i (kernel-A output, 1 global read).
__global__ __launch_bounds__(1024) void level123_lds(const float* __restrict__ Q,
                                                     const float* __restrict__ K,
                                                     const float* __restrict__ V,
                                                     float* __restrict__ Out) {
    __shared__ float Ks[73 * LROW];
    __shared__ float Vs[73 * LROW];
    const int tid = threadIdx.x;
    const int lane = tid & 63;
    const int s = lane >> 3, c = lane & 7;
    const int bh = blockIdx.x >> 2;
    const int i0 = (blockIdx.x & 3) << 4;   // first L1 query of this block
    const float* Qb = Q + (size_t)bh * NTOT * D;
    const float* Kb = K + (size_t)bh * NTOT * D;
    const float* Vb = V + (size_t)bh * NTOT * D;
    float* Ob = Out + (size_t)bh * NTOT * D;

    // ---- stage 73 K rows + 73 V rows ----
    for (int t = tid; t < 73 * 32; t += 1024) {
        const int row = t >> 5, col = (t & 31) << 2;
        const int src = (row < 64) ? (512 + row) : ((row < 72) ? (576 + row - 64) : 0);
        *(float4*)(&Ks[row * LROW + col]) = *(const float4*)(Kb + (size_t)src * D + col);
        *(float4*)(&Vs[row * LROW + col]) = *(const float4*)(Vb + (size_t)src * D + col);
    }
    __syncthreads();

    const int w = tid >> 6;
    const int i = i0 + w;        // L1 query index 0..63

    // v0n = updated row 0 = (2/3)*V[0] (analytic, from LDS)
    float4 v0n[4];
    {
        const float4* vp = (const float4*)(&Vs[72 * LROW] + (c << 4));
#pragma unroll
        for (int u = 0; u < 4; ++u) {
            float4 v = vp[u];
            v0n[u] = make_float4(v.x * (2.f * THIRD), v.y * (2.f * THIRD),
                                 v.z * (2.f * THIRD), v.w * (2.f * THIRD));
        }
    }
    // o0 = updated row 8i (kernel-A output)
    float4 o0[4];
    if (i == 0) {
#pragma unroll
        for (int u = 0; u < 4; ++u) o0[u] = v0n[u];
    } else {
        const float4* op = (const float4*)(Ob + (size_t)(8 * i) * D + (c << 4));
#pragma unroll
        for (int u = 0; u < 4; ++u) o0[u] = op[u];
    }

    // ------------------------------- Level 1 ---------------------------------
    float4 o1[4];
    {
        float4 q1[4];
        loadq(Qb + (size_t)(512 + i) * D, c, q1);
        float4 acc[4] = {{0,0,0,0},{0,0,0,0},{0,0,0,0},{0,0,0,0}};
        const float lg0q = rsum_c(dot16(q1, &Ks[72 * LROW], c)) * SCALE;
        const int sl1 = i & 7;
        const int gq = i >> 3;
        // sib: s<=sl1 -> LDS row (i&~7)+s; masked -> (lg0q, v0n)
        {
            const int r = (i & ~7) + s;
            float lg = -1e30f;
            if (s <= sl1)
                lg = rsum_c(dot16(q1, &Ks[r * LROW], c)) * SCALE;
            const float m = fmaxf(rmax_s(lg), lg0q);
            const float e = (s <= sl1) ? __expf(lg - m) : 0.f;
            const float e0 = __expf(lg0q - m);
            float zp = e;
            if (s == 0) zp += (float)(7 - sl1) * e0;
            const float inv = 1.f / rsum_s(zp);
            if (s <= sl1) vacc(e * inv, &Vs[r * LROW], c, acc);
            if (s == 0 && sl1 < 7) vacc_reg((float)(7 - sl1) * e0 * inv, v0n, acc);
        }
        // anc: s<gq -> LDS row 64+s; masked -> (lg0q, v0n)
        {
            float lg = -1e30f;
            if (s < gq)
                lg = rsum_c(dot16(q1, &Ks[(64 + s) * LROW], c)) * SCALE;
            const float m = fmaxf(rmax_s(lg), lg0q);
            const float e = (s < gq) ? __expf(lg - m) : 0.f;
            const float e0 = __expf(lg0q - m);
            float zp = e;
            if (s == 0) zp += (float)(8 - gq) * e0;
            const float inv = 1.f / rsum_s(zp);
            if (s < gq) vacc(e * inv, &Vs[(64 + s) * LROW], c, acc);
            if (s == 0) vacc_reg((float)(8 - gq) * e0 * inv, v0n, acc);  // gq<=7
        }
        // chi: s==0 -> (K row 8i global, o0); 7 masked -> (lg0q, v0n)
        {
            float lg = -1e30f;
            if (s == 0)
                lg = rsum_c(dot16(q1, Kb + (size_t)(8 * i) * D, c)) * SCALE;
            const float m = fmaxf(rmax_s(lg), lg0q);
            const float e = (s == 0) ? __expf(lg - m) : 0.f;
            const float e0 = __expf(lg0q - m);
            const float zp = (s == 0) ? (e + 7.f * e0) : 0.f;
            const float inv = 1.f / rsum_s(zp);
            if (s == 0) {
                vacc_reg(e * inv, o0, acc);
                vacc_reg(7.f * e0 * inv, v0n, acc);
            }
        }
        butterfly_acc(acc);
#pragma unroll
        for (int u = 0; u < 4; ++u)
            o1[u] = make_float4(acc[u].x * THIRD, acc[u].y * THIRD,
                                acc[u].z * THIRD, acc[u].w * THIRD);
        if (s == 0) {
            float4* orow = (float4*)(Ob + (size_t)(512 + i) * D + (c << 4));
#pragma unroll
            for (int u = 0; u < 4; ++u) orow[u] = o1[u];
        }
    }

    // ------------------- Level 2 (waves with i ≡ 0 mod 8) --------------------
    if ((i & 7) == 0) {
        const int j = i >> 3;
        float4 q2[4];
        loadq(Qb + (size_t)(576 + j) * D, c, q2);
        float4 acc[4] = {{0,0,0,0},{0,0,0,0},{0,0,0,0},{0,0,0,0}};
        const float lg0q = rsum_c(dot16(q2, &Ks[72 * LROW], c)) * SCALE;
        // sib: s<=j -> LDS row 64+s; masked -> (lg0q, v0n)
        {
            float lg = -1e30f;
            if (s <= j)
                lg = rsum_c(dot16(q2, &Ks[(64 + s) * LROW], c)) * SCALE;
            const float m = fmaxf(rmax_s(lg), lg0q);
            const float e = (s <= j) ? __expf(lg - m) : 0.f;
            const float e0 = __expf(lg0q - m);
            float zp = e;
            if (s == 0) zp += (float)(7 - j) * e0;
            const float inv = 1.f / rsum_s(zp);
            if (s <= j) vacc(e * inv, &Vs[(64 + s) * LROW], c, acc);
            if (s == 0 && j < 7) vacc_reg((float)(7 - j) * e0 * inv, v0n, acc);
        }
        // chi: s==0 -> (LDS row 8j, o1); 7 masked -> (lg0q, v0n)
        {
            float lg = -1e30f;
            if (s == 0)
                lg = rsum_c(dot16(q2, &Ks[(8 * j) * LROW], c)) * SCALE;
            const float m = fmaxf(rmax_s(lg), lg0q);
            const float e = (s == 0) ? __expf(lg - m) : 0.f;
            const float e0 = __expf(lg0q - m);
            const float zp = (s == 0) ? (e + 7.f * e0) : 0.f;
            const float inv = 1.f / rsum_s(zp);
            if (s == 0) {
                vacc_reg(e * inv, o1, acc);
                vacc_reg(7.f * e0 * inv, v0n, acc);
            }
        }
        butterfly_acc(acc);
        // anc: single always-masked entry -> weight exactly 1 on updated row 0
        float4 o2[4];
#pragma unroll
        for (int u = 0; u < 4; ++u)
            o2[u] = make_float4((acc[u].x + v0n[u].x) * THIRD, (acc[u].y + v0n[u].y) * THIRD,
                                (acc[u].z + v0n[u].z) * THIRD, (acc[u].w + v0n[u].w) * THIRD);
        if (s == 0) {
            float4* orow = (float4*)(Ob + (size_t)(576 + j) * D + (c << 4));
#pragma unroll
            for (int u = 0; u < 4; ++u) orow[u] = o2[u];
        }

        // ---------------------- Level 3 (wave with i == 0) -------------------
        if (j == 0 && i0 == 0) {
            float4 q3[4];
            loadq(Qb + (size_t)584 * D, c, q3);
            const float lg0r = rsum_c(dot16(q3, &Ks[72 * LROW], c)) * SCALE;
            // chi: s==0 -> (LDS row 64 == K row 576, o2); 7 masked -> (lg0r, v0n)
            float lg = -1e30f;
            if (s == 0)
                lg = rsum_c(dot16(q3, &Ks[64 * LROW], c)) * SCALE;
            const float m = fmaxf(rmax_s(lg), lg0r);
            const float e = (s == 0) ? __expf(lg - m) : 0.f;
            const float e0 = __expf(lg0r - m);
            const float zp = (s == 0) ? (e + 7.f * e0) : 0.f;
            const float inv = 1.f / rsum_s(zp);
            float4 acc3[4] = {{0,0,0,0},{0,0,0,0},{0,0,0,0},{0,0,0,0}};
            if (s == 0) {
                vacc_reg(e * inv, o2, acc3);
                vacc_reg(7.f * e0 * inv, v0n, acc3);
            }
            butterfly_acc(acc3);
            // sib: 8 identical entries on row 584 -> contributes ORIGINAL V[584]
            if (s == 0) {
                const float4* v584 = (const float4*)(Vb + (size_t)584 * D + (c << 4));
                float4* orow = (float4*)(Ob + (size_t)584 * D + (c << 4));
#pragma unroll
                for (int u = 0; u < 4; ++u) {
                    float4 bb = v584[u];
                    orow[u] = make_float4((acc3[u].x + bb.x) * THIRD,
                                          (acc3[u].y + bb.y) * THIRD,
                                          (acc3[u].z + bb.z) * THIRD,
                                          (acc3[u].w + bb.w) * THIRD);
                }
            }
        }
    }
}

extern "C" void kernel_launch(void* const* d_in, const int* in_sizes, int n_in,
                              void* d_out, int out_size, void* d_ws, size_t ws_size,
                              hipStream_t stream) {
    const float* Q = (const float*)d_in[0];
    const float* K = (const float*)d_in[1];
    const float* V = (const float*)d_in[2];
    float* Out = (float*)d_out;
    // A: 512 blocks x 512 threads (8 bh x 64 groups), g-limited LDS staging,
    //    2 blocks/CU for dispatch-balance slack
    hipLaunchKernelGGL(level0_lds, dim3(512), dim3(512), 0, stream, Q, K, V, Out);
    // B: 32 blocks x 1024 threads (4 per bh, 16 L1 queries each), LDS-staged
    hipLaunchKernelGGL(level123_lds, dim3(32), dim3(1024), 0, stream, Q, K, V, Out);
}

// Round 12
// 79.543 us; speedup vs baseline: 1.0278x; 1.0278x over previous
//
#include <hip/hip_runtime.h>
#include <math.h>

// Problem constants: b=2, h=4, n_tot=585, d=128, n=512, k=8
// Levels: L0 rows [0,512), L1 [512,576), L2 [576,584), L3 {584}
// Lane layout: s = lane>>3 (key slot 0..7), c = lane&7 (dim chunk of 16)
//
// Masked-entry algebra (exact, R8-proven): every masked selector slot
// contributes logit q.K[0] and value row 0; cnt identical entries == one
// term with weight cnt*e0.  Updated row 0 == (2/3)*V[0].
#define D 128
#define NTOT 585
#define SCALE 0.08838834764831845f  // 1/sqrt(128)
#define THIRD 0.33333333333333333f
#define LROW 132                    // LDS row stride (pad 4): conflict-free b128

__device__ __forceinline__ float rsum_c(float v) {  // sum over c (strides 1,2,4)
    v += __shfl_xor(v, 1, 64);
    v += __shfl_xor(v, 2, 64);
    v += __shfl_xor(v, 4, 64);
    return v;
}
__device__ __forceinline__ float rsum_s(float v) {  // sum over s (strides 8,16,32)
    v += __shfl_xor(v, 8, 64);
    v += __shfl_xor(v, 16, 64);
    v += __shfl_xor(v, 32, 64);
    return v;
}
__device__ __forceinline__ float rmax_s(float v) {
    v = fmaxf(v, __shfl_xor(v, 8, 64));
    v = fmaxf(v, __shfl_xor(v, 16, 64));
    v = fmaxf(v, __shfl_xor(v, 32, 64));
    return v;
}
__device__ __forceinline__ float dot16(const float4 q[4], const float* __restrict__ row, int c) {
    const float4* k = (const float4*)(row + (c << 4));
    float4 k0 = k[0], k1 = k[1], k2 = k[2], k3 = k[3];
    float p0 = q[0].x * k0.x + q[0].y * k0.y + q[0].z * k0.z + q[0].w * k0.w;
    float p1 = q[1].x * k1.x + q[1].y * k1.y + q[1].z * k1.z + q[1].w * k1.w;
    float p2 = q[2].x * k2.x + q[2].y * k2.y + q[2].z * k2.z + q[2].w * k2.w;
    float p3 = q[3].x * k3.x + q[3].y * k3.y + q[3].z * k3.z + q[3].w * k3.w;
    return (p0 + p1) + (p2 + p3);
}
__device__ __forceinline__ void vacc(float w, const float* __restrict__ row, int c, float4 acc[4]) {
    const float4* v = (const float4*)(row + (c << 4));
#pragma unroll
    for (int u = 0; u < 4; ++u) {
        float4 t = v[u];
        acc[u].x += w * t.x; acc[u].y += w * t.y; acc[u].z += w * t.z; acc[u].w += w * t.w;
    }
}
__device__ __forceinline__ void vacc_reg(float w, const float4 vv[4], float4 acc[4]) {
#pragma unroll
    for (int u = 0; u < 4; ++u) {
        acc[u].x += w * vv[u].x; acc[u].y += w * vv[u].y;
        acc[u].z += w * vv[u].z; acc[u].w += w * vv[u].w;
    }
}
__device__ __forceinline__ void loadq(const float* __restrict__ qrow, int c, float4 q[4]) {
    const float4* qp = (const float4*)(qrow + (c << 4));
#pragma unroll
    for (int u = 0; u < 4; ++u) q[u] = qp[u];
}
__device__ __forceinline__ void butterfly_acc(float4 acc[4]) {
#pragma unroll
    for (int u = 0; u < 4; ++u) {
        acc[u].x = rsum_s(acc[u].x);
        acc[u].y = rsum_s(acc[u].y);
        acc[u].z = rsum_s(acc[u].z);
        acc[u].w = rsum_s(acc[u].w);
    }
}

// =============== Kernel A: level 0 with full LDS staging (R9-exact) ==========
// Block = 16 consecutive L0 queries of one bh slice. 1024 threads = 16 waves,
// 1 query/wave.  LDS rows: [0,16) sib (global qb0..qb0+15), [16,80) anc
// (global 512..575), 80 = row 0.  85.5 KB -> 1 block/CU.  Best-measured (R9).
__global__ __launch_bounds__(1024) void level0_lds(const float* __restrict__ Q,
                                                   const float* __restrict__ K,
                                                   const float* __restrict__ V,
                                                   float* __restrict__ Out) {
    __shared__ float Ks[81 * LROW];
    __shared__ float Vs[81 * LROW];
    const int tid = threadIdx.x;
    const int lane = tid & 63;
    const int s = lane >> 3, c = lane & 7;
    const int bh = blockIdx.x >> 5;
    const int qb0 = (blockIdx.x & 31) << 4;  // first query of this block
    const float* Qb = Q + (size_t)bh * NTOT * D;
    const float* Kb = K + (size_t)bh * NTOT * D;
    const float* Vb = V + (size_t)bh * NTOT * D;
    float* Ob = Out + (size_t)bh * NTOT * D;

    // ---- stage 81 K rows + 81 V rows (coalesced float4) ----
    for (int t = tid; t < 81 * 32; t += 1024) {
        const int row = t >> 5, col = (t & 31) << 2;
        const int src = (row < 16) ? (qb0 + row) : ((row < 80) ? (512 + row - 16) : 0);
        *(float4*)(&Ks[row * LROW + col]) = *(const float4*)(Kb + (size_t)src * D + col);
        *(float4*)(&Vs[row * LROW + col]) = *(const float4*)(Vb + (size_t)src * D + col);
    }
    __syncthreads();

    const int w = tid >> 6;       // wave 0..15
    const int i = qb0 + w;        // this wave's query
    const int sl = i & 7;         // sib pass slots: s <= sl
    const int g = i >> 3;         // anc pass slots: j < g
    const int sibbase = w & 8;    // LDS sib row base for this wave's group

    float4 q4[4];
    loadq(Qb + (size_t)i * D, c, q4);
    float4 acc[4] = {{0,0,0,0},{0,0,0,0},{0,0,0,0},{0,0,0,0}};
    const float lg0 = rsum_c(dot16(q4, &Ks[80 * LROW], c)) * SCALE;

    // ------------------------------ sib -------------------------------------
    {
        float lg = -1e30f;
        if (s <= sl)
            lg = rsum_c(dot16(q4, &Ks[(sibbase + s) * LROW], c)) * SCALE;
        const float m = fmaxf(rmax_s(lg), lg0);
        const float e = (s <= sl) ? __expf(lg - m) : 0.f;
        const float e0 = __expf(lg0 - m);
        float zp = e;
        if (s == 0) zp += (float)(7 - sl) * e0;
        const float inv = 1.f / rsum_s(zp);
        if (s <= sl) vacc(e * inv, &Vs[(sibbase + s) * LROW], c, acc);
        if (s == 0 && sl < 7) vacc((float)(7 - sl) * e0 * inv, &Vs[80 * LROW], c, acc);
    }

    // ------------------------------ anc -------------------------------------
    // softmax over {q.K[512+j] : j<g} ∪ (64-g) copies of lg0 (value V[0]).
    {
        float lgA[8];
        float mloc = lg0;
#pragma unroll
        for (int R = 0; R < 4; ++R) {
            if (16 * R < g) {                       // wave-uniform guard
#pragma unroll
                for (int rr = 0; rr < 2; ++rr) {
                    const int r = 2 * R + rr;
                    const int j = 8 * r + s;
                    float lg = -1e30f;
                    if (j < g)                       // octet-uniform
                        lg = rsum_c(dot16(q4, &Ks[(16 + j) * LROW], c)) * SCALE;
                    lgA[r] = lg;
                    mloc = fmaxf(mloc, lg);
                }
            } else { lgA[2 * R] = -1e30f; lgA[2 * R + 1] = -1e30f; }
        }
        const float m = rmax_s(mloc);
        const float e0 = __expf(lg0 - m);
        float zp = (s == 0) ? (float)(64 - g) * e0 : 0.f;
        float eA[8];
#pragma unroll
        for (int R = 0; R < 4; ++R) {
            if (16 * R < g) {
#pragma unroll
                for (int rr = 0; rr < 2; ++rr) {
                    const int r = 2 * R + rr;
                    eA[r] = (lgA[r] > -1e29f) ? __expf(lgA[r] - m) : 0.f;
                    zp += eA[r];
                }
            }
        }
        const float inv = 1.f / rsum_s(zp);
#pragma unroll
        for (int R = 0; R < 4; ++R) {
            if (16 * R < g) {
#pragma unroll
                for (int rr = 0; rr < 2; ++rr) {
                    const int r = 2 * R + rr;
                    const int j = 8 * r + s;
                    if (j < g) vacc(eA[r] * inv, &Vs[(16 + j) * LROW], c, acc);
                }
            }
        }
        if (s == 0) vacc((float)(64 - g) * e0 * inv, &Vs[80 * LROW], c, acc);
    }
    butterfly_acc(acc);
    if (s == 0) {
        float4* orow = (float4*)(Ob + (size_t)i * D + (c << 4));
#pragma unroll
        for (int u = 0; u < 4; ++u)
            orow[u] = make_float4(acc[u].x * THIRD, acc[u].y * THIRD,
                                  acc[u].z * THIRD, acc[u].w * THIRD);
    }
}

// ====== Kernel B: levels 1+2+3, one L1 sib-group per block, light staging ====
// 64 blocks (8 bh x 8 groups) x 512 threads = 8 waves, 1 L1 query/wave:
// i = 8*gq + w.  LDS slots: [0,8) = global 512+8gq+r (sib), [8,16) = 576+r
// (anc / L2 sib), 16 = row 0.  17.9 KB -> high occupancy, ~1 load/thread.
// v0n analytic = (2/3)*V[0]; o0 = Out row 8i (kernel-A output, 1 global read).
// Wave 0 chains L2 query j=gq (chi row 512+8gq == sib slot 0); block gq==0
// wave 0 further chains L3.
__global__ __launch_bounds__(512) void level123_lds(const float* __restrict__ Q,
                                                    const float* __restrict__ K,
                                                    const float* __restrict__ V,
                                                    float* __restrict__ Out) {
    __shared__ float Ks[17 * LROW];
    __shared__ float Vs[17 * LROW];
    const int tid = threadIdx.x;
    const int lane = tid & 63;
    const int s = lane >> 3, c = lane & 7;
    const int bh = blockIdx.x >> 3;
    const int gq = blockIdx.x & 7;          // L1 sib group 0..7
    const float* Qb = Q + (size_t)bh * NTOT * D;
    const float* Kb = K + (size_t)bh * NTOT * D;
    const float* Vb = V + (size_t)bh * NTOT * D;
    float* Ob = Out + (size_t)bh * NTOT * D;

    // ---- stage 17 K rows + 17 V rows ----
    for (int t = tid; t < 17 * 32; t += 512) {
        const int row = t >> 5, col = (t & 31) << 2;
        const int src = (row < 8) ? (512 + 8 * gq + row) : ((row < 16) ? (576 + row - 8) : 0);
        *(float4*)(&Ks[row * LROW + col]) = *(const float4*)(Kb + (size_t)src * D + col);
        *(float4*)(&Vs[row * LROW + col]) = *(const float4*)(Vb + (size_t)src * D + col);
    }
    __syncthreads();

    const int w = tid >> 6;       // wave 0..7
    const int i = 8 * gq + w;     // L1 query index 0..63

    // v0n = updated row 0 = (2/3)*V[0] (analytic, from LDS slot 16)
    float4 v0n[4];
    {
        const float4* vp = (const float4*)(&Vs[16 * LROW] + (c << 4));
#pragma unroll
        for (int u = 0; u < 4; ++u) {
            float4 v = vp[u];
            v0n[u] = make_float4(v.x * (2.f * THIRD), v.y * (2.f * THIRD),
                                 v.z * (2.f * THIRD), v.w * (2.f * THIRD));
        }
    }
    // o0 = updated row 8i (kernel-A output)
    float4 o0[4];
    if (i == 0) {
#pragma unroll
        for (int u = 0; u < 4; ++u) o0[u] = v0n[u];
    } else {
        const float4* op = (const float4*)(Ob + (size_t)(8 * i) * D + (c << 4));
#pragma unroll
        for (int u = 0; u < 4; ++u) o0[u] = op[u];
    }

    // ------------------------------- Level 1 ---------------------------------
    float4 o1[4];
    {
        float4 q1[4];
        loadq(Qb + (size_t)(512 + i) * D, c, q1);
        float4 acc[4] = {{0,0,0,0},{0,0,0,0},{0,0,0,0},{0,0,0,0}};
        const float lg0q = rsum_c(dot16(q1, &Ks[16 * LROW], c)) * SCALE;
        const int sl1 = w;       // sib pass: s <= w
        // sib: s<=sl1 -> LDS slot s (global 512+8gq+s, V original); masked -> (lg0q, v0n)
        {
            float lg = -1e30f;
            if (s <= sl1)
                lg = rsum_c(dot16(q1, &Ks[s * LROW], c)) * SCALE;
            const float m = fmaxf(rmax_s(lg), lg0q);
            const float e = (s <= sl1) ? __expf(lg - m) : 0.f;
            const float e0 = __expf(lg0q - m);
            float zp = e;
            if (s == 0) zp += (float)(7 - sl1) * e0;
            const float inv = 1.f / rsum_s(zp);
            if (s <= sl1) vacc(e * inv, &Vs[s * LROW], c, acc);
            if (s == 0 && sl1 < 7) vacc_reg((float)(7 - sl1) * e0 * inv, v0n, acc);
        }
        // anc: s<gq -> LDS slot 8+s (global 576+s, V original); masked -> (lg0q, v0n)
        {
            float lg = -1e30f;
            if (s < gq)
                lg = rsum_c(dot16(q1, &Ks[(8 + s) * LROW], c)) * SCALE;
            const float m = fmaxf(rmax_s(lg), lg0q);
            const float e = (s < gq) ? __expf(lg - m) : 0.f;
            const float e0 = __expf(lg0q - m);
            float zp = e;
            if (s == 0) zp += (float)(8 - gq) * e0;
            const float inv = 1.f / rsum_s(zp);
            if (s < gq) vacc(e * inv, &Vs[(8 + s) * LROW], c, acc);
            if (s == 0) vacc_reg((float)(8 - gq) * e0 * inv, v0n, acc);  // gq<=7
        }
        // chi: s==0 -> (K row 8i global, o0); 7 masked -> (lg0q, v0n)
        {
            float lg = -1e30f;
            if (s == 0)
                lg = rsum_c(dot16(q1, Kb + (size_t)(8 * i) * D, c)) * SCALE;
            const float m = fmaxf(rmax_s(lg), lg0q);
            const float e = (s == 0) ? __expf(lg - m) : 0.f;
            const float e0 = __expf(lg0q - m);
            const float zp = (s == 0) ? (e + 7.f * e0) : 0.f;
            const float inv = 1.f / rsum_s(zp);
            if (s == 0) {
                vacc_reg(e * inv, o0, acc);
                vacc_reg(7.f * e0 * inv, v0n, acc);
            }
        }
        butterfly_acc(acc);
#pragma unroll
        for (int u = 0; u < 4; ++u)
            o1[u] = make_float4(acc[u].x * THIRD, acc[u].y * THIRD,
                                acc[u].z * THIRD, acc[u].w * THIRD);
        if (s == 0) {
            float4* orow = (float4*)(Ob + (size_t)(512 + i) * D + (c << 4));
#pragma unroll
            for (int u = 0; u < 4; ++u) orow[u] = o1[u];
        }
    }

    // ------------------- Level 2 (wave 0: query j == gq) ---------------------
    if (w == 0) {
        const int j = gq;
        float4 q2[4];
        loadq(Qb + (size_t)(576 + j) * D, c, q2);
        float4 acc[4] = {{0,0,0,0},{0,0,0,0},{0,0,0,0},{0,0,0,0}};
        const float lg0q = rsum_c(dot16(q2, &Ks[16 * LROW], c)) * SCALE;
        // sib: s<=j -> LDS slot 8+s (global 576+s, V original); masked -> (lg0q, v0n)
        {
            float lg = -1e30f;
            if (s <= j)
                lg = rsum_c(dot16(q2, &Ks[(8 + s) * LROW], c)) * SCALE;
            const float m = fmaxf(rmax_s(lg), lg0q);
            const float e = (s <= j) ? __expf(lg - m) : 0.f;
            const float e0 = __expf(lg0q - m);
            float zp = e;
            if (s == 0) zp += (float)(7 - j) * e0;
            const float inv = 1.f / rsum_s(zp);
            if (s <= j) vacc(e * inv, &Vs[(8 + s) * LROW], c, acc);
            if (s == 0 && j < 7) vacc_reg((float)(7 - j) * e0 * inv, v0n, acc);
        }
        // chi: s==0 -> (K slot 0 == row 512+8j, o1 regs); 7 masked -> (lg0q, v0n)
        {
            float lg = -1e30f;
            if (s == 0)
                lg = rsum_c(dot16(q2, &Ks[0], c)) * SCALE;
            const float m = fmaxf(rmax_s(lg), lg0q);
            const float e = (s == 0) ? __expf(lg - m) : 0.f;
            const float e0 = __expf(lg0q - m);
            const float zp = (s == 0) ? (e + 7.f * e0) : 0.f;
            const float inv = 1.f / rsum_s(zp);
            if (s == 0) {
                vacc_reg(e * inv, o1, acc);
                vacc_reg(7.f * e0 * inv, v0n, acc);
            }
        }
        butterfly_acc(acc);
        // anc: single always-masked entry -> weight exactly 1 on updated row 0
        float4 o2[4];
#pragma unroll
        for (int u = 0; u < 4; ++u)
            o2[u] = make_float4((acc[u].x + v0n[u].x) * THIRD, (acc[u].y + v0n[u].y) * THIRD,
                                (acc[u].z + v0n[u].z) * THIRD, (acc[u].w + v0n[u].w) * THIRD);
        if (s == 0) {
            float4* orow = (float4*)(Ob + (size_t)(576 + j) * D + (c << 4));
#pragma unroll
            for (int u = 0; u < 4; ++u) orow[u] = o2[u];
        }

        // ---------------------- Level 3 (block gq == 0) ----------------------
        if (j == 0) {
            float4 q3[4];
            loadq(Qb + (size_t)584 * D, c, q3);
            const float lg0r = rsum_c(dot16(q3, &Ks[16 * LROW], c)) * SCALE;
            // chi: s==0 -> (K slot 8 == row 576, o2 regs); 7 masked -> (lg0r, v0n)
            float lg = -1e30f;
            if (s == 0)
                lg = rsum_c(dot16(q3, &Ks[8 * LROW], c)) * SCALE;
            const float m = fmaxf(rmax_s(lg), lg0r);
            const float e = (s == 0) ? __expf(lg - m) : 0.f;
            const float e0 = __expf(lg0r - m);
            const float zp = (s == 0) ? (e + 7.f * e0) : 0.f;
            const float inv = 1.f / rsum_s(zp);
            float4 acc3[4] = {{0,0,0,0},{0,0,0,0},{0,0,0,0},{0,0,0,0}};
            if (s == 0) {
                vacc_reg(e * inv, o2, acc3);
                vacc_reg(7.f * e0 * inv, v0n, acc3);
            }
            butterfly_acc(acc3);
            // sib: 8 identical entries on row 584 -> contributes ORIGINAL V[584]
            if (s == 0) {
                const float4* v584 = (const float4*)(Vb + (size_t)584 * D + (c << 4));
                float4* orow = (float4*)(Ob + (size_t)584 * D + (c << 4));
#pragma unroll
                for (int u = 0; u < 4; ++u) {
                    float4 bb = v584[u];
                    orow[u] = make_float4((acc3[u].x + bb.x) * THIRD,
                                          (acc3[u].y + bb.y) * THIRD,
                                          (acc3[u].z + bb.z) * THIRD,
                                          (acc3[u].w + bb.w) * THIRD);
                }
            }
        }
    }
}

extern "C" void kernel_launch(void* const* d_in, const int* in_sizes, int n_in,
                              void* d_out, int out_size, void* d_ws, size_t ws_size,
                              hipStream_t stream) {
    const float* Q = (const float*)d_in[0];
    const float* K = (const float*)d_in[1];
    const float* V = (const float*)d_in[2];
    float* Out = (float*)d_out;
    // A: 256 blocks x 1024 threads (R9-exact, best measured)
    hipLaunchKernelGGL(level0_lds, dim3(256), dim3(1024), 0, stream, Q, K, V, Out);
    // B: 64 blocks x 512 threads (one L1 sib-group per block, 17-row staging)
    hipLaunchKernelGGL(level123_lds, dim3(64), dim3(512), 0, stream, Q, K, V, Out);
}

// Round 13
// 76.592 us; speedup vs baseline: 1.0674x; 1.0385x over previous
//
#include <hip/hip_runtime.h>
#include <math.h>

// Problem constants: b=2, h=4, n_tot=585, d=128, n=512, k=8
// Levels: L0 rows [0,512), L1 [512,576), L2 [576,584), L3 {584}
// Lane layout: s = lane>>3 (key slot 0..7), c = lane&7 (dim chunk of 16)
//
// Masked-entry algebra (exact, R8-proven): every masked selector slot
// contributes logit q.K[0] and value row 0; cnt identical entries == one
// term with weight cnt*e0.  Updated row 0 == (2/3)*V[0].
//
// Single-launch closure: L0 of row 8i has sl=0 (sib needs only row 8i) and
// anc rows 512..512+i-1 — block (bh,qb0) stages rows qb0..qb0+15 (contains
// 8i for i = qb0/8, qb0/8+1) AND all anc rows, so the block recomputes o0
// for its two L1 queries from its own LDS, then chains L1/L2/L3 in-block.
#define D 128
#define NTOT 585
#define SCALE 0.08838834764831845f  // 1/sqrt(128)
#define THIRD 0.33333333333333333f
#define LROW 132                    // LDS row stride (pad 4): conflict-free b128

__device__ __forceinline__ float rsum_c(float v) {  // sum over c (strides 1,2,4)
    v += __shfl_xor(v, 1, 64);
    v += __shfl_xor(v, 2, 64);
    v += __shfl_xor(v, 4, 64);
    return v;
}
__device__ __forceinline__ float rsum_s(float v) {  // sum over s (strides 8,16,32)
    v += __shfl_xor(v, 8, 64);
    v += __shfl_xor(v, 16, 64);
    v += __shfl_xor(v, 32, 64);
    return v;
}
__device__ __forceinline__ float rmax_s(float v) {
    v = fmaxf(v, __shfl_xor(v, 8, 64));
    v = fmaxf(v, __shfl_xor(v, 16, 64));
    v = fmaxf(v, __shfl_xor(v, 32, 64));
    return v;
}
__device__ __forceinline__ float dot16(const float4 q[4], const float* __restrict__ row, int c) {
    const float4* k = (const float4*)(row + (c << 4));
    float4 k0 = k[0], k1 = k[1], k2 = k[2], k3 = k[3];
    float p0 = q[0].x * k0.x + q[0].y * k0.y + q[0].z * k0.z + q[0].w * k0.w;
    float p1 = q[1].x * k1.x + q[1].y * k1.y + q[1].z * k1.z + q[1].w * k1.w;
    float p2 = q[2].x * k2.x + q[2].y * k2.y + q[2].z * k2.z + q[2].w * k2.w;
    float p3 = q[3].x * k3.x + q[3].y * k3.y + q[3].z * k3.z + q[3].w * k3.w;
    return (p0 + p1) + (p2 + p3);
}
__device__ __forceinline__ void vacc(float w, const float* __restrict__ row, int c, float4 acc[4]) {
    const float4* v = (const float4*)(row + (c << 4));
#pragma unroll
    for (int u = 0; u < 4; ++u) {
        float4 t = v[u];
        acc[u].x += w * t.x; acc[u].y += w * t.y; acc[u].z += w * t.z; acc[u].w += w * t.w;
    }
}
__device__ __forceinline__ void vacc_reg(float w, const float4 vv[4], float4 acc[4]) {
#pragma unroll
    for (int u = 0; u < 4; ++u) {
        acc[u].x += w * vv[u].x; acc[u].y += w * vv[u].y;
        acc[u].z += w * vv[u].z; acc[u].w += w * vv[u].w;
    }
}
__device__ __forceinline__ void loadq(const float* __restrict__ qrow, int c, float4 q[4]) {
    const float4* qp = (const float4*)(qrow + (c << 4));
#pragma unroll
    for (int u = 0; u < 4; ++u) q[u] = qp[u];
}
__device__ __forceinline__ void butterfly_acc(float4 acc[4]) {
#pragma unroll
    for (int u = 0; u < 4; ++u) {
        acc[u].x = rsum_s(acc[u].x);
        acc[u].y = rsum_s(acc[u].y);
        acc[u].z = rsum_s(acc[u].z);
        acc[u].w = rsum_s(acc[u].w);
    }
}

// anc softmax contribution for an L0-style query (g pass rows from LDS anc
// slots [16,80), (64-g) masked copies of lg0 with value Vs[80]): R9-exact path.
__device__ __forceinline__ void anc_l0(const float4 q4[4], int g, int s, int c,
                                       const float* __restrict__ Ks,
                                       const float* __restrict__ Vs,
                                       float lg0, float4 acc[4]) {
    float lgA[8];
    float mloc = lg0;
#pragma unroll
    for (int R = 0; R < 4; ++R) {
        if (16 * R < g) {                       // wave-uniform guard
#pragma unroll
            for (int rr = 0; rr < 2; ++rr) {
                const int r = 2 * R + rr;
                const int j = 8 * r + s;
                float lg = -1e30f;
                if (j < g)                       // octet-uniform
                    lg = rsum_c(dot16(q4, &Ks[(16 + j) * LROW], c)) * SCALE;
                lgA[r] = lg;
                mloc = fmaxf(mloc, lg);
            }
        } else { lgA[2 * R] = -1e30f; lgA[2 * R + 1] = -1e30f; }
    }
    const float m = rmax_s(mloc);
    const float e0 = __expf(lg0 - m);
    float zp = (s == 0) ? (float)(64 - g) * e0 : 0.f;
    float eA[8];
#pragma unroll
    for (int R = 0; R < 4; ++R) {
        if (16 * R < g) {
#pragma unroll
            for (int rr = 0; rr < 2; ++rr) {
                const int r = 2 * R + rr;
                eA[r] = (lgA[r] > -1e29f) ? __expf(lgA[r] - m) : 0.f;
                zp += eA[r];
            }
        }
    }
    const float inv = 1.f / rsum_s(zp);
#pragma unroll
    for (int R = 0; R < 4; ++R) {
        if (16 * R < g) {
#pragma unroll
            for (int rr = 0; rr < 2; ++rr) {
                const int r = 2 * R + rr;
                const int j = 8 * r + s;
                if (j < g) vacc(eA[r] * inv, &Vs[(16 + j) * LROW], c, acc);
            }
        }
    }
    if (s == 0) vacc((float)(64 - g) * e0 * inv, &Vs[80 * LROW], c, acc);
}

// ================== single fused kernel: L0 + L1 + L2 + L3 ===================
// 256 blocks (8 bh x 32) x 1024 threads = 16 waves.
// LDS rows: [0,16) = global qb0..qb0+15; [16,80) = 512..575; 80 = row 0;
// [81,89) = 576..583.  89 rows x 132 x 4 x 2 arrays = 94 KB -> 1 block/CU.
__global__ __launch_bounds__(1024) void sequoia_fused(const float* __restrict__ Q,
                                                      const float* __restrict__ K,
                                                      const float* __restrict__ V,
                                                      float* __restrict__ Out) {
    __shared__ float Ks[89 * LROW];
    __shared__ float Vs[89 * LROW];
    const int tid = threadIdx.x;
    const int lane = tid & 63;
    const int s = lane >> 3, c = lane & 7;
    const int bh = blockIdx.x >> 5;
    const int qb0 = (blockIdx.x & 31) << 4;  // first L0 query of this block
    const float* Qb = Q + (size_t)bh * NTOT * D;
    const float* Kb = K + (size_t)bh * NTOT * D;
    const float* Vb = V + (size_t)bh * NTOT * D;
    float* Ob = Out + (size_t)bh * NTOT * D;

    // ---- stage 89 K rows + 89 V rows (coalesced float4) ----
    for (int t = tid; t < 89 * 32; t += 1024) {
        const int row = t >> 5, col = (t & 31) << 2;
        int src;
        if (row < 16)      src = qb0 + row;
        else if (row < 80) src = 512 + row - 16;
        else if (row == 80) src = 0;
        else               src = 576 + (row - 81);
        *(float4*)(&Ks[row * LROW + col]) = *(const float4*)(Kb + (size_t)src * D + col);
        *(float4*)(&Vs[row * LROW + col]) = *(const float4*)(Vb + (size_t)src * D + col);
    }
    __syncthreads();

    const int w = tid >> 6;       // wave 0..15

    // ========================= Phase L0 (all waves) ==========================
    {
        const int i = qb0 + w;        // this wave's L0 query
        const int sl = i & 7;
        const int g = i >> 3;
        const int sibbase = w & 8;    // LDS sib row base for this wave's group

        float4 q4[4];
        loadq(Qb + (size_t)i * D, c, q4);
        float4 acc[4] = {{0,0,0,0},{0,0,0,0},{0,0,0,0},{0,0,0,0}};
        const float lg0 = rsum_c(dot16(q4, &Ks[80 * LROW], c)) * SCALE;
        // sib
        {
            float lg = -1e30f;
            if (s <= sl)
                lg = rsum_c(dot16(q4, &Ks[(sibbase + s) * LROW], c)) * SCALE;
            const float m = fmaxf(rmax_s(lg), lg0);
            const float e = (s <= sl) ? __expf(lg - m) : 0.f;
            const float e0 = __expf(lg0 - m);
            float zp = e;
            if (s == 0) zp += (float)(7 - sl) * e0;
            const float inv = 1.f / rsum_s(zp);
            if (s <= sl) vacc(e * inv, &Vs[(sibbase + s) * LROW], c, acc);
            if (s == 0 && sl < 7) vacc((float)(7 - sl) * e0 * inv, &Vs[80 * LROW], c, acc);
        }
        // anc
        anc_l0(q4, g, s, c, Ks, Vs, lg0, acc);
        butterfly_acc(acc);
        if (s == 0) {
            float4* orow = (float4*)(Ob + (size_t)i * D + (c << 4));
#pragma unroll
            for (int u = 0; u < 4; ++u)
                orow[u] = make_float4(acc[u].x * THIRD, acc[u].y * THIRD,
                                      acc[u].z * THIRD, acc[u].w * THIRD);
        }
    }

    // ================= Phase chain (waves 0..1): L1 (+L2,+L3) ================
    if (w < 2) {
        const int ci = (qb0 >> 3) + w;   // L1 query index 0..63 (8*ci = qb0+8w)

        // v0n = updated row 0 = (2/3)*V[0] (analytic, from LDS)
        float4 v0n[4];
        {
            const float4* vp = (const float4*)(&Vs[80 * LROW] + (c << 4));
#pragma unroll
            for (int u = 0; u < 4; ++u) {
                float4 v = vp[u];
                v0n[u] = make_float4(v.x * (2.f * THIRD), v.y * (2.f * THIRD),
                                     v.z * (2.f * THIRD), v.w * (2.f * THIRD));
            }
        }

        // ---- o0 = updated row 8*ci, recomputed ALL-LDS (sl=0 shortcut) ----
        float4 o0[4];
        if (ci == 0) {
#pragma unroll
            for (int u = 0; u < 4; ++u) o0[u] = v0n[u];
        } else {
            float4 q0[4];
            loadq(Qb + (size_t)(8 * ci) * D, c, q0);
            float4 acc[4] = {{0,0,0,0},{0,0,0,0},{0,0,0,0},{0,0,0,0}};
            const float lg0 = rsum_c(dot16(q0, &Ks[80 * LROW], c)) * SCALE;
            // sib (sl=0): pass row 8*ci = LDS sib slot 8w
            {
                float lg = -1e30f;
                if (s == 0)
                    lg = rsum_c(dot16(q0, &Ks[(8 * w) * LROW], c)) * SCALE;
                const float m = fmaxf(rmax_s(lg), lg0);
                const float e = (s == 0) ? __expf(lg - m) : 0.f;
                const float e0 = __expf(lg0 - m);
                float zp = e;
                if (s == 0) zp += 7.f * e0;
                const float inv = 1.f / rsum_s(zp);
                if (s == 0) {
                    vacc(e * inv, &Vs[(8 * w) * LROW], c, acc);
                    vacc(7.f * e0 * inv, &Vs[80 * LROW], c, acc);
                }
            }
            anc_l0(q0, ci, s, c, Ks, Vs, lg0, acc);  // g = ci
            butterfly_acc(acc);
#pragma unroll
            for (int u = 0; u < 4; ++u)
                o0[u] = make_float4(acc[u].x * THIRD, acc[u].y * THIRD,
                                    acc[u].z * THIRD, acc[u].w * THIRD);
        }

        // ------------------------------ Level 1 ------------------------------
        float4 o1[4];
        {
            float4 q1[4];
            loadq(Qb + (size_t)(512 + ci) * D, c, q1);
            float4 acc[4] = {{0,0,0,0},{0,0,0,0},{0,0,0,0},{0,0,0,0}};
            const float lg0q = rsum_c(dot16(q1, &Ks[80 * LROW], c)) * SCALE;
            const int sl1 = ci & 7;
            const int gq = ci >> 3;
            // sib: s<=sl1 -> LDS anc slot 16+(ci&~7)+s (V original); masked -> v0n
            {
                const int slot = 16 + (ci & ~7) + s;
                float lg = -1e30f;
                if (s <= sl1)
                    lg = rsum_c(dot16(q1, &Ks[slot * LROW], c)) * SCALE;
                const float m = fmaxf(rmax_s(lg), lg0q);
                const float e = (s <= sl1) ? __expf(lg - m) : 0.f;
                const float e0 = __expf(lg0q - m);
                float zp = e;
                if (s == 0) zp += (float)(7 - sl1) * e0;
                const float inv = 1.f / rsum_s(zp);
                if (s <= sl1) vacc(e * inv, &Vs[slot * LROW], c, acc);
                if (s == 0 && sl1 < 7) vacc_reg((float)(7 - sl1) * e0 * inv, v0n, acc);
            }
            // anc: s<gq -> LDS slot 81+s (V original); masked -> v0n
            {
                float lg = -1e30f;
                if (s < gq)
                    lg = rsum_c(dot16(q1, &Ks[(81 + s) * LROW], c)) * SCALE;
                const float m = fmaxf(rmax_s(lg), lg0q);
                const float e = (s < gq) ? __expf(lg - m) : 0.f;
                const float e0 = __expf(lg0q - m);
                float zp = e;
                if (s == 0) zp += (float)(8 - gq) * e0;
                const float inv = 1.f / rsum_s(zp);
                if (s < gq) vacc(e * inv, &Vs[(81 + s) * LROW], c, acc);
                if (s == 0) vacc_reg((float)(8 - gq) * e0 * inv, v0n, acc);  // gq<=7
            }
            // chi: s==0 -> (K row 8*ci = LDS sib slot 8w, o0 regs); masked -> v0n
            {
                float lg = -1e30f;
                if (s == 0)
                    lg = rsum_c(dot16(q1, &Ks[(8 * w) * LROW], c)) * SCALE;
                const float m = fmaxf(rmax_s(lg), lg0q);
                const float e = (s == 0) ? __expf(lg - m) : 0.f;
                const float e0 = __expf(lg0q - m);
                const float zp = (s == 0) ? (e + 7.f * e0) : 0.f;
                const float inv = 1.f / rsum_s(zp);
                if (s == 0) {
                    vacc_reg(e * inv, o0, acc);
                    vacc_reg(7.f * e0 * inv, v0n, acc);
                }
            }
            butterfly_acc(acc);
#pragma unroll
            for (int u = 0; u < 4; ++u)
                o1[u] = make_float4(acc[u].x * THIRD, acc[u].y * THIRD,
                                    acc[u].z * THIRD, acc[u].w * THIRD);
            if (s == 0) {
                float4* orow = (float4*)(Ob + (size_t)(512 + ci) * D + (c << 4));
#pragma unroll
                for (int u = 0; u < 4; ++u) orow[u] = o1[u];
            }
        }

        // ---------------- Level 2 (blocks qb0%64==0, wave 0) -----------------
        if (w == 0 && (ci & 7) == 0) {
            const int j = ci >> 3;   // == qb0/64, 0..7
            float4 q2[4];
            loadq(Qb + (size_t)(576 + j) * D, c, q2);
            float4 acc[4] = {{0,0,0,0},{0,0,0,0},{0,0,0,0},{0,0,0,0}};
            const float lg0q = rsum_c(dot16(q2, &Ks[80 * LROW], c)) * SCALE;
            // sib: s<=j -> LDS slot 81+s (V original); masked -> v0n
            {
                float lg = -1e30f;
                if (s <= j)
                    lg = rsum_c(dot16(q2, &Ks[(81 + s) * LROW], c)) * SCALE;
                const float m = fmaxf(rmax_s(lg), lg0q);
                const float e = (s <= j) ? __expf(lg - m) : 0.f;
                const float e0 = __expf(lg0q - m);
                float zp = e;
                if (s == 0) zp += (float)(7 - j) * e0;
                const float inv = 1.f / rsum_s(zp);
                if (s <= j) vacc(e * inv, &Vs[(81 + s) * LROW], c, acc);
                if (s == 0 && j < 7) vacc_reg((float)(7 - j) * e0 * inv, v0n, acc);
            }
            // chi: s==0 -> (K row 512+8j = LDS anc slot 16+8j, o1 regs); masked -> v0n
            {
                float lg = -1e30f;
                if (s == 0)
                    lg = rsum_c(dot16(q2, &Ks[(16 + 8 * j) * LROW], c)) * SCALE;
                const float m = fmaxf(rmax_s(lg), lg0q);
                const float e = (s == 0) ? __expf(lg - m) : 0.f;
                const float e0 = __expf(lg0q - m);
                const float zp = (s == 0) ? (e + 7.f * e0) : 0.f;
                const float inv = 1.f / rsum_s(zp);
                if (s == 0) {
                    vacc_reg(e * inv, o1, acc);
                    vacc_reg(7.f * e0 * inv, v0n, acc);
                }
            }
            butterfly_acc(acc);
            // anc: single always-masked entry -> weight exactly 1 on v0n
            float4 o2[4];
#pragma unroll
            for (int u = 0; u < 4; ++u)
                o2[u] = make_float4((acc[u].x + v0n[u].x) * THIRD,
                                    (acc[u].y + v0n[u].y) * THIRD,
                                    (acc[u].z + v0n[u].z) * THIRD,
                                    (acc[u].w + v0n[u].w) * THIRD);
            if (s == 0) {
                float4* orow = (float4*)(Ob + (size_t)(576 + j) * D + (c << 4));
#pragma unroll
                for (int u = 0; u < 4; ++u) orow[u] = o2[u];
            }

            // ------------------- Level 3 (block qb0 == 0) --------------------
            if (j == 0) {
                float4 q3[4];
                loadq(Qb + (size_t)584 * D, c, q3);
                const float lg0r = rsum_c(dot16(q3, &Ks[80 * LROW], c)) * SCALE;
                // chi: s==0 -> (K row 576 = LDS slot 81, o2 regs); masked -> v0n
                float lg = -1e30f;
                if (s == 0)
                    lg = rsum_c(dot16(q3, &Ks[81 * LROW], c)) * SCALE;
                const float m = fmaxf(rmax_s(lg), lg0r);
                const float e = (s == 0) ? __expf(lg - m) : 0.f;
                const float e0 = __expf(lg0r - m);
                const float zp = (s == 0) ? (e + 7.f * e0) : 0.f;
                const float inv = 1.f / rsum_s(zp);
                float4 acc3[4] = {{0,0,0,0},{0,0,0,0},{0,0,0,0},{0,0,0,0}};
                if (s == 0) {
                    vacc_reg(e * inv, o2, acc3);
                    vacc_reg(7.f * e0 * inv, v0n, acc3);
                }
                butterfly_acc(acc3);
                // sib: 8 identical entries on row 584 -> ORIGINAL V[584]
                if (s == 0) {
                    const float4* v584 = (const float4*)(Vb + (size_t)584 * D + (c << 4));
                    float4* orow = (float4*)(Ob + (size_t)584 * D + (c << 4));
#pragma unroll
                    for (int u = 0; u < 4; ++u) {
                        float4 bb = v584[u];
                        orow[u] = make_float4((acc3[u].x + bb.x) * THIRD,
                                              (acc3[u].y + bb.y) * THIRD,
                                              (acc3[u].z + bb.z) * THIRD,
                                              (acc3[u].w + bb.w) * THIRD);
                    }
                }
            }
        }
    }
}

extern "C" void kernel_launch(void* const* d_in, const int* in_sizes, int n_in,
                              void* d_out, int out_size, void* d_ws, size_t ws_size,
                              hipStream_t stream) {
    const float* Q = (const float*)d_in[0];
    const float* K = (const float*)d_in[1];
    const float* V = (const float*)d_in[2];
    float* Out = (float*)d_out;
    // ONE launch: 256 blocks x 1024 threads (8 bh x 32 blocks of 16 L0
    // queries); each block also chains its 2 L1 queries (+L2/L3 where owned)
    // from its own LDS — no cross-block dependencies, no second kernel.
    hipLaunchKernelGGL(sequoia_fused, dim3(256), dim3(1024), 0, stream, Q, K, V, Out);
}